// Round 14
// baseline (252.589 us; speedup 1.0000x reference)
//
#include <hip/hip_runtime.h>

#define NP 16
#define D 768
#define NBLK 512   // all co-resident; 1563 = 3*512 + 27 grid-stride iters
#define NTHR 256   // 4 waves
#define RPI 128    // rows per block-iteration (32 per wave)
#define DSL 192    // d-slice per wave
#define NM 12      // persistent accumulators: [chunk 0..2][e 0..3]

// ws float layout:
//  [0, 6144)                  PTfrag (bf16 B-fragments of normalized protos)
//  [6144, 6144+NBLK*12288)    per-block partial sums
//  [then NBLK*16]             per-block partial counts

typedef short short8 __attribute__((ext_vector_type(8)));
typedef float f32x4 __attribute__((ext_vector_type(4)));

static __device__ __forceinline__ unsigned f2bf_u(float f) {
    unsigned u = __float_as_uint(f);
    u += 0x7FFF + ((u >> 16) & 1);  // RTNE
    return u >> 16;
}
static __device__ __forceinline__ unsigned pack2bf(float lo, float hi) {
    return f2bf_u(lo) | (f2bf_u(hi) << 16);
}

__global__ __launch_bounds__(64) void setup_kernel(const float* __restrict__ protos,
                                                   float* __restrict__ ws) {
    const int p = blockIdx.x, lane = threadIdx.x;
    const float* pr = protos + p * D;
    float v[12];
    float ns = 0.f;
#pragma unroll
    for (int j = 0; j < 12; ++j) {
        v[j] = pr[lane + 64 * j];
        ns = fmaf(v[j], v[j], ns);
    }
#pragma unroll
    for (int m = 1; m < 64; m <<= 1) ns += __shfl_xor(ns, m);
    const float rn = 1.0f / sqrtf(ns);
    // B-fragment scatter (verified r6-r13): Pn[p][c], c=s*32+g*8+jj -> ushort idx (s*64+g*16+p)*8+jj
    unsigned short* ptf = (unsigned short*)ws;
#pragma unroll
    for (int j = 0; j < 12; ++j) {
        const int c = lane + 64 * j;
        const int s = c >> 5, sub = c & 31, g = sub >> 3, jj = sub & 7;
        ptf[(unsigned)((s * 64 + g * 16 + p) * 8 + jj)] = (unsigned short)f2bf_u(v[j] * rn);
    }
}

__global__ __launch_bounds__(NTHR, 2) void fused_kernel(const float* __restrict__ x,
                                                        const float* __restrict__ ws,
                                                        float* __restrict__ gpart,
                                                        float* __restrict__ gcnt,
                                                        int nrows, int niter) {
    __shared__ short8 sPT[24 * 64];  // 24 KB proto B-fragments
    __shared__ float rS[RPI];
    __shared__ int aS[RPI];
    __shared__ float C[NP];

    const int tid = threadIdx.x, w = tid >> 6, lane = tid & 63;
    const int r15 = lane & 15, g = lane >> 4;

    {
        const uint4* src = (const uint4*)ws;
        uint4* dst = (uint4*)sPT;
        for (int i = tid; i < 1536; i += NTHR) dst[i] = src[i];
    }
    if (tid < NP) C[tid] = 0.f;
    __syncthreads();

    f32x4 acc[NM];  // [ch*4+e]; output col n of MFMA e = d (ch*64 + n*4 + e)
#pragma unroll
    for (int m = 0; m < NM; ++m) acc[m] = (f32x4){0.f, 0.f, 0.f, 0.f};

    for (int it = blockIdx.x; it < niter; it += NBLK) {
        const int rb = it * RPI;

        // ---------- phase A: sim + norm + argmax for this wave's 32 rows ----------
#pragma unroll
        for (int h = 0; h < 2; ++h) {
            const int base = rb + w * 32 + h * 16;
            const int rowc = min(base + r15, nrows - 1);
            const float* xr = x + (size_t)rowc * D + (g << 3);
            const short8* bp = sPT + lane;
            f32x4 se = {0.f, 0.f, 0.f, 0.f}, so = {0.f, 0.f, 0.f, 0.f};
            float nse = 0.f, nso = 0.f;
#pragma unroll
            for (int s = 0; s < 24; s += 2) {
                const float4 f0 = *(const float4*)(xr + s * 32);
                const float4 f1 = *(const float4*)(xr + s * 32 + 4);
                const float4 h0 = *(const float4*)(xr + s * 32 + 32);
                const float4 h1 = *(const float4*)(xr + s * 32 + 36);
                nse = fmaf(f0.x, f0.x, fmaf(f0.y, f0.y, fmaf(f0.z, f0.z, fmaf(f0.w, f0.w, nse))));
                nse = fmaf(f1.x, f1.x, fmaf(f1.y, f1.y, fmaf(f1.z, f1.z, fmaf(f1.w, f1.w, nse))));
                nso = fmaf(h0.x, h0.x, fmaf(h0.y, h0.y, fmaf(h0.z, h0.z, fmaf(h0.w, h0.w, nso))));
                nso = fmaf(h1.x, h1.x, fmaf(h1.y, h1.y, fmaf(h1.z, h1.z, fmaf(h1.w, h1.w, nso))));
                uint4 ae, ao;
                ae.x = pack2bf(f0.x, f0.y); ae.y = pack2bf(f0.z, f0.w);
                ae.z = pack2bf(f1.x, f1.y); ae.w = pack2bf(f1.z, f1.w);
                ao.x = pack2bf(h0.x, h0.y); ao.y = pack2bf(h0.z, h0.w);
                ao.z = pack2bf(h1.x, h1.y); ao.w = pack2bf(h1.z, h1.w);
                se = __builtin_amdgcn_mfma_f32_16x16x32_bf16(
                    __builtin_bit_cast(short8, ae), bp[s * 64], se, 0, 0, 0);
                so = __builtin_amdgcn_mfma_f32_16x16x32_bf16(
                    __builtin_bit_cast(short8, ao), bp[(s + 1) * 64], so, 0, 0, 0);
            }
            f32x4 sc;
#pragma unroll
            for (int r = 0; r < 4; ++r) sc[r] = se[r] + so[r];
            float ns = nse + nso;
            ns += __shfl_xor(ns, 16);
            ns += __shfl_xor(ns, 32);
            const float rn = 1.0f / sqrtf(ns);

            int ar[4];
#pragma unroll
            for (int r = 0; r < 4; ++r) {
                float bv = sc[r];
                int bi = r15;
#pragma unroll
                for (int m = 1; m <= 8; m <<= 1) {
                    const float ov = __shfl_xor(bv, m);
                    const int oi = __shfl_xor(bi, m);
                    if (ov > bv || (ov == bv && oi < bi)) { bv = ov; bi = oi; }
                }
                ar[r] = bi;
            }
            if (r15 == 0) {
#pragma unroll
                for (int r = 0; r < 4; ++r) {
                    aS[w * 32 + h * 16 + g * 4 + r] = ar[r];
                    if (base + g * 4 + r < nrows) atomicAdd(&C[ar[r]], 1.0f);
                }
            }
            if (lane < 16) rS[w * 32 + h * 16 + lane] = (base + lane < nrows) ? rn : 0.f;
        }
        __syncthreads();

        // ---------- phase B: one-hot MFMA segment-sum, coalesced float4 reads ----------
#pragma unroll
        for (int kc = 0; kc < 4; ++kc) {
            const int nb = kc * 32 + (g << 3);  // this lane's 8-row base (local)
            float rnv[8];
            int an[8];
#pragma unroll
            for (int j = 0; j < 8; ++j) {
                rnv[j] = rS[nb + j];
                an[j] = aS[nb + j];
            }
            uint4 au;
            {
                unsigned t0, t1;
                t0 = (an[0] == r15) ? 0x3F80u : 0u; t1 = (an[1] == r15) ? 0x3F80u : 0u;
                au.x = t0 | (t1 << 16);
                t0 = (an[2] == r15) ? 0x3F80u : 0u; t1 = (an[3] == r15) ? 0x3F80u : 0u;
                au.y = t0 | (t1 << 16);
                t0 = (an[4] == r15) ? 0x3F80u : 0u; t1 = (an[5] == r15) ? 0x3F80u : 0u;
                au.z = t0 | (t1 << 16);
                t0 = (an[6] == r15) ? 0x3F80u : 0u; t1 = (an[7] == r15) ? 0x3F80u : 0u;
                au.w = t0 | (t1 << 16);
            }
            const short8 afrag = __builtin_bit_cast(short8, au);

            const float* rp[8];
#pragma unroll
            for (int j = 0; j < 8; ++j) {
                int rr = rb + nb + j;
                rr = rr < nrows ? rr : nrows - 1;
                rp[j] = x + (size_t)rr * D + w * DSL + r15 * 4;  // float4-aligned gather
            }
#pragma unroll
            for (int ch = 0; ch < 3; ++ch) {
                f32x4 v4[8];
#pragma unroll
                for (int j = 0; j < 8; ++j) {
                    const f32x4 t = *(const f32x4*)(rp[j] + ch * 64);
                    v4[j] = t * rnv[j];  // fp32 rn*x
                }
#pragma unroll
                for (int e = 0; e < 4; ++e) {
                    uint4 bu;
                    bu.x = pack2bf(v4[0][e], v4[1][e]);
                    bu.y = pack2bf(v4[2][e], v4[3][e]);
                    bu.z = pack2bf(v4[4][e], v4[5][e]);
                    bu.w = pack2bf(v4[6][e], v4[7][e]);
                    acc[ch * 4 + e] = __builtin_amdgcn_mfma_f32_16x16x32_bf16(
                        afrag, __builtin_bit_cast(short8, bu), acc[ch * 4 + e], 0, 0, 0);
                }
            }
        }
        __syncthreads();  // aS/rS reused next iteration
    }

    // ---------- flush: non-atomic per-block partials (de-interleave e) ----------
    // acc[ch*4+e][r]: proto = g*4+r, d = w*DSL + ch*64 + r15*4 + e
    float* gp = gpart + (size_t)blockIdx.x * (NP * D);
#pragma unroll
    for (int ch = 0; ch < 3; ++ch)
#pragma unroll
        for (int r = 0; r < 4; ++r) {
            float4 o;
            o.x = acc[ch * 4 + 0][r];
            o.y = acc[ch * 4 + 1][r];
            o.z = acc[ch * 4 + 2][r];
            o.w = acc[ch * 4 + 3][r];
            *(float4*)&gp[(g * 4 + r) * D + w * DSL + ch * 64 + r15 * 4] = o;
        }
    if (tid < NP) gcnt[blockIdx.x * NP + tid] = C[tid];
}

__global__ __launch_bounds__(256) void finalize_kernel(const float* __restrict__ gpart,
                                                       const float* __restrict__ gcnt,
                                                       float* __restrict__ out) {
    __shared__ float cnt[NP];
    const int tid = threadIdx.x;
    if (tid < NP) {
        float c = 0.f;
        for (int b = 0; b < NBLK; ++b) c += gcnt[b * NP + tid];
        cnt[tid] = c;
    }
    __syncthreads();
    const int i = blockIdx.x * 256 + tid;
    if (i < NP * D) {
        float s = 0.f;
#pragma unroll 8
        for (int b = 0; b < NBLK; ++b) s += gpart[(size_t)b * (NP * D) + i];
        const float c = cnt[i / D];
        out[i] = (c > 0.f) ? s / fmaxf(c, 1.0f) : 0.f;
    }
}

extern "C" void kernel_launch(void* const* d_in, const int* in_sizes, int n_in,
                              void* d_out, int out_size, void* d_ws, size_t ws_size,
                              hipStream_t stream) {
    const float* x = (const float*)d_in[0];
    const float* protos = (const float*)d_in[1];
    float* ws = (float*)d_ws;
    float* out = (float*)d_out;
    const int nrows = in_sizes[0] / D;             // 200000
    const int niter = (nrows + RPI - 1) / RPI;     // 1563

    float* gpart = ws + 6144;
    float* gcnt = ws + 6144 + (size_t)NBLK * (NP * D);

    setup_kernel<<<16, 64, 0, stream>>>(protos, ws);
    fused_kernel<<<NBLK, NTHR, 0, stream>>>(x, ws, gpart, gcnt, nrows, niter);
    finalize_kernel<<<(NP * D + 255) / 256, 256, 0, stream>>>(gpart, gcnt, out);
}

// Round 15
// 224.111 us; speedup vs baseline: 1.1271x; 1.1271x over previous
//
#include <hip/hip_runtime.h>

#define NP 16
#define D 768
#define NBLK 512   // all co-resident; niter = 3125 = 6*512 + 53 grid-stride iters
#define NTHR 256   // 4 waves
#define RPI 64     // rows per block-iteration (16 per wave = one MFMA tile)
#define DSL 192    // d-slice per wave
#define NM 12      // persistent accumulators

// ws float layout:
//  [0, 6144)                  PTfrag (bf16 B-fragments of normalized protos)
//  [6144, 6144+NBLK*12288)    per-block partial sums
//  [then NBLK*16]             per-block partial counts

typedef short short8 __attribute__((ext_vector_type(8)));
typedef float f32x4 __attribute__((ext_vector_type(4)));

static __device__ __forceinline__ unsigned f2bf_u(float f) {
    unsigned u = __float_as_uint(f);
    u += 0x7FFF + ((u >> 16) & 1);  // RTNE
    return u >> 16;
}
static __device__ __forceinline__ unsigned pack2bf(float lo, float hi) {
    return f2bf_u(lo) | (f2bf_u(hi) << 16);
}

__global__ __launch_bounds__(64) void setup_kernel(const float* __restrict__ protos,
                                                   float* __restrict__ ws) {
    const int p = blockIdx.x, lane = threadIdx.x;
    const float* pr = protos + p * D;
    float v[12];
    float ns = 0.f;
#pragma unroll
    for (int j = 0; j < 12; ++j) {
        v[j] = pr[lane + 64 * j];
        ns = fmaf(v[j], v[j], ns);
    }
#pragma unroll
    for (int m = 1; m < 64; m <<= 1) ns += __shfl_xor(ns, m);
    const float rn = 1.0f / sqrtf(ns);
    // B-fragment scatter (verified r6-r14): Pn[p][c], c=s*32+g*8+jj -> ushort idx (s*64+g*16+p)*8+jj
    unsigned short* ptf = (unsigned short*)ws;
#pragma unroll
    for (int j = 0; j < 12; ++j) {
        const int c = lane + 64 * j;
        const int s = c >> 5, sub = c & 31, g = sub >> 3, jj = sub & 7;
        ptf[(unsigned)((s * 64 + g * 16 + p) * 8 + jj)] = (unsigned short)f2bf_u(v[j] * rn);
    }
}

__global__ __launch_bounds__(NTHR, 2) void fused_kernel(const float* __restrict__ x,
                                                        const float* __restrict__ ws,
                                                        float* __restrict__ gpart,
                                                        float* __restrict__ gcnt,
                                                        int nrows, int niter) {
    __shared__ short8 sPT[24 * 64];  // 24 KB proto B-fragments
    __shared__ float rS[RPI];
    __shared__ int aS[RPI];
    __shared__ float C[NP];

    const int tid = threadIdx.x, w = tid >> 6, lane = tid & 63;
    const int r15 = lane & 15, g = lane >> 4;

    {
        const uint4* src = (const uint4*)ws;
        uint4* dst = (uint4*)sPT;
        for (int i = tid; i < 1536; i += NTHR) dst[i] = src[i];
    }
    if (tid < NP) C[tid] = 0.f;
    __syncthreads();

    f32x4 acc[NM];  // persistent segment-sum accumulators (48 VGPR)
#pragma unroll
    for (int m = 0; m < NM; ++m) acc[m] = (f32x4){0.f, 0.f, 0.f, 0.f};

    for (int it = blockIdx.x; it < niter; it += NBLK) {
        const int rb = it * RPI;

        // ---------- phase A: sim + norm + argmax for this wave's 16 rows ----------
        {
            const int base = rb + w * 16;
            const int rowc = min(base + r15, nrows - 1);
            const float* xr = x + (size_t)rowc * D + (g << 3);
            const short8* bp = sPT + lane;
            f32x4 se = {0.f, 0.f, 0.f, 0.f}, so = {0.f, 0.f, 0.f, 0.f};
            float nse = 0.f, nso = 0.f;
#pragma unroll
            for (int s = 0; s < 24; s += 2) {
                const float4 f0 = *(const float4*)(xr + s * 32);
                const float4 f1 = *(const float4*)(xr + s * 32 + 4);
                const float4 h0 = *(const float4*)(xr + s * 32 + 32);
                const float4 h1 = *(const float4*)(xr + s * 32 + 36);
                nse = fmaf(f0.x, f0.x, fmaf(f0.y, f0.y, fmaf(f0.z, f0.z, fmaf(f0.w, f0.w, nse))));
                nse = fmaf(f1.x, f1.x, fmaf(f1.y, f1.y, fmaf(f1.z, f1.z, fmaf(f1.w, f1.w, nse))));
                nso = fmaf(h0.x, h0.x, fmaf(h0.y, h0.y, fmaf(h0.z, h0.z, fmaf(h0.w, h0.w, nso))));
                nso = fmaf(h1.x, h1.x, fmaf(h1.y, h1.y, fmaf(h1.z, h1.z, fmaf(h1.w, h1.w, nso))));
                uint4 ae, ao;
                ae.x = pack2bf(f0.x, f0.y); ae.y = pack2bf(f0.z, f0.w);
                ae.z = pack2bf(f1.x, f1.y); ae.w = pack2bf(f1.z, f1.w);
                ao.x = pack2bf(h0.x, h0.y); ao.y = pack2bf(h0.z, h0.w);
                ao.z = pack2bf(h1.x, h1.y); ao.w = pack2bf(h1.z, h1.w);
                se = __builtin_amdgcn_mfma_f32_16x16x32_bf16(
                    __builtin_bit_cast(short8, ae), bp[s * 64], se, 0, 0, 0);
                so = __builtin_amdgcn_mfma_f32_16x16x32_bf16(
                    __builtin_bit_cast(short8, ao), bp[(s + 1) * 64], so, 0, 0, 0);
            }
            f32x4 sc;
#pragma unroll
            for (int r = 0; r < 4; ++r) sc[r] = se[r] + so[r];
            float ns = nse + nso;
            ns += __shfl_xor(ns, 16);
            ns += __shfl_xor(ns, 32);
            const float rn = 1.0f / sqrtf(ns);

            int ar[4];
#pragma unroll
            for (int r = 0; r < 4; ++r) {
                float bv = sc[r];
                int bi = r15;
#pragma unroll
                for (int m = 1; m <= 8; m <<= 1) {
                    const float ov = __shfl_xor(bv, m);
                    const int oi = __shfl_xor(bi, m);
                    if (ov > bv || (ov == bv && oi < bi)) { bv = ov; bi = oi; }
                }
                ar[r] = bi;
            }
            if (r15 == 0) {
#pragma unroll
                for (int r = 0; r < 4; ++r) {
                    aS[w * 16 + g * 4 + r] = ar[r];
                    if (base + g * 4 + r < nrows) atomicAdd(&C[ar[r]], 1.0f);
                }
            }
            if (lane < 16) rS[w * 16 + lane] = (base + lane < nrows) ? rn : 0.f;
        }
        __syncthreads();

        // ---------- phase B: one-hot MFMA segment-sum over all 64 rows ----------
#pragma unroll
        for (int kc = 0; kc < 2; ++kc) {
            const int nb = kc * 32 + (g << 3);  // this lane's 8-row base (local)
            float rnv[8];
            int an[8];
#pragma unroll
            for (int j = 0; j < 8; ++j) {
                rnv[j] = rS[nb + j];
                an[j] = aS[nb + j];
            }
            uint4 au;
            {
                unsigned t0, t1;
                t0 = (an[0] == r15) ? 0x3F80u : 0u; t1 = (an[1] == r15) ? 0x3F80u : 0u;
                au.x = t0 | (t1 << 16);
                t0 = (an[2] == r15) ? 0x3F80u : 0u; t1 = (an[3] == r15) ? 0x3F80u : 0u;
                au.y = t0 | (t1 << 16);
                t0 = (an[4] == r15) ? 0x3F80u : 0u; t1 = (an[5] == r15) ? 0x3F80u : 0u;
                au.z = t0 | (t1 << 16);
                t0 = (an[6] == r15) ? 0x3F80u : 0u; t1 = (an[7] == r15) ? 0x3F80u : 0u;
                au.w = t0 | (t1 << 16);
            }
            const short8 afrag = __builtin_bit_cast(short8, au);

            const float* rp[8];
#pragma unroll
            for (int j = 0; j < 8; ++j) {
                int rr = rb + nb + j;
                rr = rr < nrows ? rr : nrows - 1;
                rp[j] = x + (size_t)rr * D + w * DSL + r15;
            }
#pragma unroll
            for (int m = 0; m < NM; ++m) {
                float v[8];
#pragma unroll
                for (int j = 0; j < 8; ++j) v[j] = rp[j][m * 16] * rnv[j];  // fp32 rn*x
                uint4 bu;
                bu.x = pack2bf(v[0], v[1]); bu.y = pack2bf(v[2], v[3]);
                bu.z = pack2bf(v[4], v[5]); bu.w = pack2bf(v[6], v[7]);
                acc[m] = __builtin_amdgcn_mfma_f32_16x16x32_bf16(
                    afrag, __builtin_bit_cast(short8, bu), acc[m], 0, 0, 0);
            }
        }
        __syncthreads();  // aS/rS reused next iteration
    }

    // ---------- flush: non-atomic per-block partials ----------
    // lane holds D[proto = g*4+r][d = w*DSL + m*16 + r15]
    float* gp = gpart + (size_t)blockIdx.x * (NP * D);
#pragma unroll
    for (int m = 0; m < NM; ++m)
#pragma unroll
        for (int r = 0; r < 4; ++r)
            gp[(g * 4 + r) * D + w * DSL + m * 16 + r15] = acc[m][r];
    if (tid < NP) gcnt[blockIdx.x * NP + tid] = C[tid];
}

__global__ __launch_bounds__(256) void finalize_kernel(const float* __restrict__ gpart,
                                                       const float* __restrict__ gcnt,
                                                       float* __restrict__ out) {
    __shared__ float cnt[NP];
    const int tid = threadIdx.x;
    if (tid < NP) {
        float c = 0.f;
        for (int b = 0; b < NBLK; ++b) c += gcnt[b * NP + tid];
        cnt[tid] = c;
    }
    __syncthreads();
    const int i = blockIdx.x * 256 + tid;
    if (i < NP * D) {
        float s = 0.f;
#pragma unroll 8
        for (int b = 0; b < NBLK; ++b) s += gpart[(size_t)b * (NP * D) + i];
        const float c = cnt[i / D];
        out[i] = (c > 0.f) ? s / fmaxf(c, 1.0f) : 0.f;
    }
}

extern "C" void kernel_launch(void* const* d_in, const int* in_sizes, int n_in,
                              void* d_out, int out_size, void* d_ws, size_t ws_size,
                              hipStream_t stream) {
    const float* x = (const float*)d_in[0];
    const float* protos = (const float*)d_in[1];
    float* ws = (float*)d_ws;
    float* out = (float*)d_out;
    const int nrows = in_sizes[0] / D;             // 200000
    const int niter = (nrows + RPI - 1) / RPI;     // 3125

    float* gpart = ws + 6144;
    float* gcnt = ws + 6144 + (size_t)NBLK * (NP * D);

    setup_kernel<<<16, 64, 0, stream>>>(protos, ws);
    fused_kernel<<<NBLK, NTHR, 0, stream>>>(x, ws, gpart, gcnt, nrows, niter);
    finalize_kernel<<<(NP * D + 255) / 256, 256, 0, stream>>>(gpart, gcnt, out);
}